// Round 3
// baseline (13.689 us; speedup 1.0000x reference)
//
#include <hip/hip_runtime.h>
#include <math.h>

// Problem constants (reference: B=64, S=512, K=64, D=16)
#define NTOT   32768          // B*S
#define BATCH  64
#define KCAT   64
#define DDIM   16
#define F_LOG2PI 1.8378770664093453f
#define CAT_PRIOR -4.1588830833596715f   // -log(64)

constexpr int LPN  = 8;    // lanes per point-group (split of K)
constexpr int GPN  = 4;    // points (n) per thread
constexpr int BLK  = 256;  // threads per block
constexpr int NPB  = (BLK / LPN) * GPN;   // 128 points per block
constexpr int NBLK = NTOT / NPB;          // 256 blocks
constexpr int ROWS = 36;   // padded LDS row stride in dwords (bank-conflict-free)

__global__ __launch_bounds__(BLK) void lce_main(
    const int*   __restrict__ z,
    const float* __restrict__ zn,
    const float* __restrict__ t,
    const float* __restrict__ ls,
    float*       __restrict__ out,
    float*       __restrict__ partial)
{
    // comb row k: [0..15]=exp(-ls), [16..31]=t, [32]=kc, [33]=sum_ls, [34..35] pad
    __shared__ float comb[KCAT * ROWS];
    __shared__ float est [KCAT * ROWS];   // [0..15] = exp(+ls)
    __shared__ float red[4];

    const int tid = threadIdx.x;

    for (int i = tid; i < KCAT * DDIM; i += BLK) {
        const int k = i >> 4, d = i & 15;
        const float lv = ls[i];
        comb[k * ROWS + d]      = expf(-lv);   // precise: multiplies into 2M evals
        comb[k * ROWS + 16 + d] = t[i];
        est [k * ROWS + d]      = expf(lv);
    }
    if (tid < KCAT) {
        float s = 0.f;
        #pragma unroll
        for (int d = 0; d < DDIM; ++d) s += ls[tid * DDIM + d];
        comb[tid * ROWS + 32] = -0.5f * F_LOG2PI * DDIM - s + CAT_PRIOR; // kc
        comb[tid * ROWS + 33] = s;                                        // sum log_s
    }
    __syncthreads();

    const int q  = tid & (LPN - 1);
    const int n0 = blockIdx.x * NPB + (tid >> 3) * GPN;

    float ze[GPN][DDIM];
    float log_point[GPN], base[GPN];
    int   cat[GPN];

    // ---- forward flow: z_enc, init_log_p, ldj_fwd ----
    #pragma unroll
    for (int nn = 0; nn < GPN; ++nn) {
        const int n = n0 + nn;
        const int c = z[n];
        cat[nn] = c;
        const float sumls = comb[c * ROWS + 33];
        const float4* zp = (const float4*)(zn + (long)n * DDIM);
        float ss = 0.f;
        #pragma unroll
        for (int j = 0; j < 4; ++j) {
            const float4 v  = zp[j];
            const float4 tc = *(const float4*)&comb[c * ROWS + 16 + j * 4];
            const float4 ec = *(const float4*)&est [c * ROWS + j * 4];
            ze[nn][j*4+0] = (v.x + tc.x) * ec.x;
            ze[nn][j*4+1] = (v.y + tc.y) * ec.y;
            ze[nn][j*4+2] = (v.z + tc.z) * ec.z;
            ze[nn][j*4+3] = (v.w + tc.w) * ec.w;
            ss = fmaf(v.x, v.x, ss);
            ss = fmaf(v.y, v.y, ss);
            ss = fmaf(v.z, v.z, ss);
            ss = fmaf(v.w, v.w, ss);
        }
        const float init_lp = -0.5f * ss - 8.f * F_LOG2PI;
        base[nn]      = init_lp - sumls;          // init_log_p - ldj_fwd
        log_point[nn] = base[nn] + CAT_PRIOR;
    }

    // ---- expand-to-K inverse flow: lane q handles k = q, q+8, ..., q+56 ----
    float dn[GPN][KCAT / LPN];
    float mx[GPN];
    #pragma unroll
    for (int nn = 0; nn < GPN; ++nn) mx[nn] = -1e30f;

    #pragma unroll
    for (int j = 0; j < KCAT / LPN; ++j) {
        const int k = q + j * LPN;
        float is_[DDIM], tr[DDIM];
        #pragma unroll
        for (int jj = 0; jj < 4; ++jj) {
            *(float4*)&is_[jj*4] = *(const float4*)&comb[k * ROWS + jj * 4];
            *(float4*)&tr [jj*4] = *(const float4*)&comb[k * ROWS + 16 + jj * 4];
        }
        const float kc = comb[k * ROWS + 32];
        #pragma unroll
        for (int nn = 0; nn < GPN; ++nn) {
            float acc = 0.f;
            #pragma unroll
            for (int d = 0; d < DDIM; ++d) {
                const float zb = fmaf(ze[nn][d], is_[d], -tr[d]);
                acc = fmaf(zb, zb, acc);
            }
            float dv = fmaf(-0.5f, acc, kc);
            dn[nn][j] = (k == cat[nn]) ? log_point[nn] : dv;
            mx[nn] = fmaxf(mx[nn], dn[nn][j]);
        }
    }

    // ---- logsumexp across 8 lanes + ldj_loc ----
    float ldj_acc = 0.f;
    #pragma unroll
    for (int nn = 0; nn < GPN; ++nn) {
        float m = mx[nn];
        m = fmaxf(m, __shfl_xor(m, 1));
        m = fmaxf(m, __shfl_xor(m, 2));
        m = fmaxf(m, __shfl_xor(m, 4));
        float se = 0.f;
        #pragma unroll
        for (int j = 0; j < KCAT / LPN; ++j) se += __expf(dn[nn][j] - m);
        se += __shfl_xor(se, 1);
        se += __shfl_xor(se, 2);
        se += __shfl_xor(se, 4);
        const float log_den = m + __logf(se);
        ldj_acc += (log_point[nn] - log_den) - base[nn];
    }

    // ---- write z_out: 16 float4 chunks per group, lane q writes chunks q, q+8 ----
    float4* op = (float4*)(out + (long)n0 * DDIM);
#define CH(nn, jj) make_float4(ze[nn][4*(jj)+0], ze[nn][4*(jj)+1], ze[nn][4*(jj)+2], ze[nn][4*(jj)+3])
    switch (q) {
        case 0: op[0] = CH(0,0); op[ 8] = CH(2,0); break;
        case 1: op[1] = CH(0,1); op[ 9] = CH(2,1); break;
        case 2: op[2] = CH(0,2); op[10] = CH(2,2); break;
        case 3: op[3] = CH(0,3); op[11] = CH(2,3); break;
        case 4: op[4] = CH(1,0); op[12] = CH(3,0); break;
        case 5: op[5] = CH(1,1); op[13] = CH(3,1); break;
        case 6: op[6] = CH(1,2); op[14] = CH(3,2); break;
        case 7: op[7] = CH(1,3); op[15] = CH(3,3); break;
    }
#undef CH

    // ---- ldj partial: lanes within a group hold identical ldj_acc, so only
    //      reduce across group bits 3..5 of the wave ----
    float v = ldj_acc;
    v += __shfl_xor(v, 8);
    v += __shfl_xor(v, 16);
    v += __shfl_xor(v, 32);
    if ((tid & 63) == 0) red[tid >> 6] = v;
    __syncthreads();
    if (tid == 0) partial[blockIdx.x] = red[0] + red[1] + red[2] + red[3];
}

__global__ void lce_fin(const float* __restrict__ partial, float* __restrict__ ldj)
{
    const int b = threadIdx.x;
    if (b < BATCH) {
        // 4 blocks per batch (NPB=128, S=512)
        float s = 0.f;
        #pragma unroll
        for (int j = 0; j < 4; ++j) s += partial[b * 4 + j];
        ldj[b] = s;
    }
}

extern "C" void kernel_launch(void* const* d_in, const int* in_sizes, int n_in,
                              void* d_out, int out_size, void* d_ws, size_t ws_size,
                              hipStream_t stream)
{
    const int*   z  = (const int*)  d_in[0];
    const float* zn = (const float*)d_in[1];
    const float* t  = (const float*)d_in[2];
    const float* ls = (const float*)d_in[3];
    float* out     = (float*)d_out;              // [NTOT*DDIM] z_out
    float* ldj     = out + (long)NTOT * DDIM;    // [BATCH]
    float* partial = (float*)d_ws;               // [NBLK]

    lce_main<<<NBLK, BLK, 0, stream>>>(z, zn, t, ls, out, partial);
    lce_fin<<<1, 64, 0, stream>>>(partial, ldj);
}

// Round 4
// 13.007 us; speedup vs baseline: 1.0524x; 1.0524x over previous
//
#include <hip/hip_runtime.h>
#include <math.h>

// Problem constants (reference: B=64, S=512, K=64, D=16)
#define NTOT   32768          // B*S
#define BATCH  64
#define KCAT   64
#define DDIM   16
#define F_LOG2PI 1.8378770664093453f
#define CAT_PRIOR -4.1588830833596715f   // -log(64)

constexpr int LPN  = 8;    // lanes per point-group (split of K)
constexpr int GPN  = 2;    // points (n) per thread  (4->2: halve regs, double waves)
constexpr int BLK  = 256;  // threads per block
constexpr int NPB  = (BLK / LPN) * GPN;   // 64 points per block
constexpr int NBLK = NTOT / NPB;          // 512 blocks -> 2 blocks/CU, 2 waves/SIMD
constexpr int ROWS = 36;   // padded LDS row stride in dwords (bank-conflict-free)

__global__ __launch_bounds__(BLK, 2) void lce_main(
    const int*   __restrict__ z,
    const float* __restrict__ zn,
    const float* __restrict__ t,
    const float* __restrict__ ls,
    float*       __restrict__ out,
    float*       __restrict__ partial)
{
    // comb row k: [0..15]=exp(-ls), [16..31]=t, [32]=kc, [33]=sum_ls, [34..35] pad
    __shared__ float comb[KCAT * ROWS];
    __shared__ float est [KCAT * ROWS];   // [0..15] = exp(+ls)
    __shared__ float red[4];

    const int tid = threadIdx.x;

    for (int i = tid; i < KCAT * DDIM; i += BLK) {
        const int k = i >> 4, d = i & 15;
        const float lv = ls[i];
        comb[k * ROWS + d]      = expf(-lv);   // precise: multiplies into 2M evals
        comb[k * ROWS + 16 + d] = t[i];
        est [k * ROWS + d]      = expf(lv);
    }
    if (tid < KCAT) {
        float s = 0.f;
        #pragma unroll
        for (int d = 0; d < DDIM; ++d) s += ls[tid * DDIM + d];
        comb[tid * ROWS + 32] = -0.5f * F_LOG2PI * DDIM - s + CAT_PRIOR; // kc
        comb[tid * ROWS + 33] = s;                                        // sum log_s
    }
    __syncthreads();

    const int q  = tid & (LPN - 1);
    const int n0 = blockIdx.x * NPB + (tid >> 3) * GPN;

    float ze[GPN][DDIM];
    float log_point[GPN], base[GPN];
    int   cat[GPN];

    // ---- forward flow: z_enc, init_log_p, ldj_fwd ----
    #pragma unroll
    for (int nn = 0; nn < GPN; ++nn) {
        const int n = n0 + nn;
        const int c = z[n];
        cat[nn] = c;
        const float sumls = comb[c * ROWS + 33];
        const float4* zp = (const float4*)(zn + (long)n * DDIM);
        float ss = 0.f;
        #pragma unroll
        for (int j = 0; j < 4; ++j) {
            const float4 v  = zp[j];
            const float4 tc = *(const float4*)&comb[c * ROWS + 16 + j * 4];
            const float4 ec = *(const float4*)&est [c * ROWS + j * 4];
            ze[nn][j*4+0] = (v.x + tc.x) * ec.x;
            ze[nn][j*4+1] = (v.y + tc.y) * ec.y;
            ze[nn][j*4+2] = (v.z + tc.z) * ec.z;
            ze[nn][j*4+3] = (v.w + tc.w) * ec.w;
            ss = fmaf(v.x, v.x, ss);
            ss = fmaf(v.y, v.y, ss);
            ss = fmaf(v.z, v.z, ss);
            ss = fmaf(v.w, v.w, ss);
        }
        const float init_lp = -0.5f * ss - 8.f * F_LOG2PI;
        base[nn]      = init_lp - sumls;          // init_log_p - ldj_fwd
        log_point[nn] = base[nn] + CAT_PRIOR;
    }

    // ---- expand-to-K inverse flow: lane q handles k = q, q+8, ..., q+56 ----
    float dn[GPN][KCAT / LPN];
    float mx[GPN];
    #pragma unroll
    for (int nn = 0; nn < GPN; ++nn) mx[nn] = -1e30f;

    #pragma unroll
    for (int j = 0; j < KCAT / LPN; ++j) {
        const int k = q + j * LPN;
        float is_[DDIM], tr[DDIM];
        #pragma unroll
        for (int jj = 0; jj < 4; ++jj) {
            *(float4*)&is_[jj*4] = *(const float4*)&comb[k * ROWS + jj * 4];
            *(float4*)&tr [jj*4] = *(const float4*)&comb[k * ROWS + 16 + jj * 4];
        }
        const float kc = comb[k * ROWS + 32];
        #pragma unroll
        for (int nn = 0; nn < GPN; ++nn) {
            float acc = 0.f;
            #pragma unroll
            for (int d = 0; d < DDIM; ++d) {
                const float zb = fmaf(ze[nn][d], is_[d], -tr[d]);
                acc = fmaf(zb, zb, acc);
            }
            float dv = fmaf(-0.5f, acc, kc);
            dn[nn][j] = (k == cat[nn]) ? log_point[nn] : dv;
            mx[nn] = fmaxf(mx[nn], dn[nn][j]);
        }
    }

    // ---- logsumexp across 8 lanes + ldj_loc ----
    float ldj_acc = 0.f;
    #pragma unroll
    for (int nn = 0; nn < GPN; ++nn) {
        float m = mx[nn];
        m = fmaxf(m, __shfl_xor(m, 1));
        m = fmaxf(m, __shfl_xor(m, 2));
        m = fmaxf(m, __shfl_xor(m, 4));
        float se = 0.f;
        #pragma unroll
        for (int j = 0; j < KCAT / LPN; ++j) se += __expf(dn[nn][j] - m);
        se += __shfl_xor(se, 1);
        se += __shfl_xor(se, 2);
        se += __shfl_xor(se, 4);
        const float log_den = m + __logf(se);
        ldj_acc += (log_point[nn] - log_den) - base[nn];
    }

    // ---- write z_out: 8 float4 chunks per group (2 points), lane q writes chunk q
    float4* op = (float4*)(out + (long)n0 * DDIM);
#define CH(nn, jj) make_float4(ze[nn][4*(jj)+0], ze[nn][4*(jj)+1], ze[nn][4*(jj)+2], ze[nn][4*(jj)+3])
    switch (q) {
        case 0: op[0] = CH(0,0); break;
        case 1: op[1] = CH(0,1); break;
        case 2: op[2] = CH(0,2); break;
        case 3: op[3] = CH(0,3); break;
        case 4: op[4] = CH(1,0); break;
        case 5: op[5] = CH(1,1); break;
        case 6: op[6] = CH(1,2); break;
        case 7: op[7] = CH(1,3); break;
    }
#undef CH

    // ---- ldj partial: lanes within a group hold identical ldj_acc, so only
    //      reduce across group bits 3..5 of the wave ----
    float v = ldj_acc;
    v += __shfl_xor(v, 8);
    v += __shfl_xor(v, 16);
    v += __shfl_xor(v, 32);
    if ((tid & 63) == 0) red[tid >> 6] = v;
    __syncthreads();
    if (tid == 0) partial[blockIdx.x] = red[0] + red[1] + red[2] + red[3];
}

__global__ void lce_fin(const float* __restrict__ partial, float* __restrict__ ldj)
{
    const int b = threadIdx.x;
    if (b < BATCH) {
        // 8 blocks per batch (NPB=64, S=512); partial is 16B-aligned (d_ws)
        const float4* p4 = (const float4*)(partial + b * 8);
        const float4 a = p4[0], c = p4[1];
        ldj[b] = ((a.x + a.y) + (a.z + a.w)) + ((c.x + c.y) + (c.z + c.w));
    }
}

extern "C" void kernel_launch(void* const* d_in, const int* in_sizes, int n_in,
                              void* d_out, int out_size, void* d_ws, size_t ws_size,
                              hipStream_t stream)
{
    const int*   z  = (const int*)  d_in[0];
    const float* zn = (const float*)d_in[1];
    const float* t  = (const float*)d_in[2];
    const float* ls = (const float*)d_in[3];
    float* out     = (float*)d_out;              // [NTOT*DDIM] z_out
    float* ldj     = out + (long)NTOT * DDIM;    // [BATCH]
    float* partial = (float*)d_ws;               // [NBLK]

    lce_main<<<NBLK, BLK, 0, stream>>>(z, zn, t, ls, out, partial);
    lce_fin<<<1, 64, 0, stream>>>(partial, ldj);
}